// Round 10
// baseline (791.861 us; speedup 1.0000x reference)
//
#include <hip/hip_runtime.h>
#include <hip/hip_bf16.h>

// AttentionForQuantizer: q/k/v proj + RMSNorm + logits(32768x4096) + argmax + gather.
// R10: INSTRUMENTATION ROUND 2. R9 measured refine_in_context = 166us (735-569).
// Ledger now implies mfma_logits ~ 280-310us vs a 40-80us cycle model — a gap I
// refuse to theorize away after two failed attribution rounds. This round runs
// mfma_logits TWICE (pass 2 rewrites bit-identical values to the same addresses;
// deterministic; also absorbs pass 1's dirty-L2 writeback, mirroring R8 context).
// Single refine, everything else byte-identical to R8 (passed).
// Read: total ~850-880 => mfma is the sink (restructure it next);
//       total ~700-730 => ~150us is inter-kernel overhead (fuse kernels next).

#define NTOK 32768
#define NCODE 4096
#define DIM 256

typedef __bf16 bf16x8 __attribute__((ext_vector_type(8)));
typedef float f32x4 __attribute__((ext_vector_type(4)));

// ---------------- fp32 GEMM: Y[M][256] = X[M][256] @ W[256][256] + bias ----------------
// 128x128 tile per block, 256 threads, 8x8 per thread, BK=32.
__global__ __launch_bounds__(256, 2)
void gemm_xw256(const float* __restrict__ X, const float* __restrict__ W,
                const float* __restrict__ bias, float* __restrict__ Y)
{
    __shared__ __align__(16) float Xs[32][132];  // [kk][m], padded
    __shared__ __align__(16) float Ws[32][132];  // [kk][n], padded
    const int t  = threadIdx.x;
    const int tm = t >> 4;         // 0..15
    const int tn = t & 15;         // 0..15
    const int mb = blockIdx.x * 128;
    const int nb = blockIdx.y * 128;

    float acc[8][8];
    #pragma unroll
    for (int i = 0; i < 8; ++i)
        #pragma unroll
        for (int j = 0; j < 8; ++j) acc[i][j] = 0.f;

    const int sxm = t >> 1;          // X staging: row 0..127
    const int sxh = (t & 1) * 16;    // X staging: k-half base
    const int swk = t >> 3;          // W staging: kk 0..31
    const int swc = (t & 7) * 16;    // W staging: col base

    for (int kb = 0; kb < 256; kb += 32) {
        float4 xv[4], wv[4];
        #pragma unroll
        for (int i = 0; i < 4; ++i) {
            xv[i] = *(const float4*)&X[(size_t)(mb + sxm) * 256 + kb + sxh + 4 * i];
            wv[i] = *(const float4*)&W[(size_t)(kb + swk) * 256 + nb + swc + 4 * i];
        }
        __syncthreads();  // previous iteration's LDS reads done before overwrite
        #pragma unroll
        for (int i = 0; i < 4; ++i) {
            Xs[sxh + 4*i + 0][sxm] = xv[i].x;
            Xs[sxh + 4*i + 1][sxm] = xv[i].y;
            Xs[sxh + 4*i + 2][sxm] = xv[i].z;
            Xs[sxh + 4*i + 3][sxm] = xv[i].w;
            *(float4*)&Ws[swk][swc + 4*i] = wv[i];
        }
        __syncthreads();
        #pragma unroll 8
        for (int kk = 0; kk < 32; ++kk) {
            float4 a0 = *(const float4*)&Xs[kk][tm*8];
            float4 a1 = *(const float4*)&Xs[kk][tm*8 + 4];
            float4 b0 = *(const float4*)&Ws[kk][tn*8];
            float4 b1 = *(const float4*)&Ws[kk][tn*8 + 4];
            float av[8] = {a0.x,a0.y,a0.z,a0.w,a1.x,a1.y,a1.z,a1.w};
            float bw[8] = {b0.x,b0.y,b0.z,b0.w,b1.x,b1.y,b1.z,b1.w};
            #pragma unroll
            for (int i = 0; i < 8; ++i)
                #pragma unroll
                for (int j = 0; j < 8; ++j)
                    acc[i][j] = fmaf(av[i], bw[j], acc[i][j]);
        }
    }

    float4 bb0 = *(const float4*)&bias[nb + tn*8];
    float4 bb1 = *(const float4*)&bias[nb + tn*8 + 4];
    float bb[8] = {bb0.x,bb0.y,bb0.z,bb0.w,bb1.x,bb1.y,bb1.z,bb1.w};
    #pragma unroll
    for (int i = 0; i < 8; ++i) {
        const size_t row = (size_t)(mb + tm*8 + i);
        float4 o0 = {acc[i][0]+bb[0], acc[i][1]+bb[1], acc[i][2]+bb[2], acc[i][3]+bb[3]};
        float4 o1 = {acc[i][4]+bb[4], acc[i][5]+bb[5], acc[i][6]+bb[6], acc[i][7]+bb[7]};
        *(float4*)&Y[row*256 + nb + tn*8]     = o0;
        *(float4*)&Y[row*256 + nb + tn*8 + 4] = o1;
    }
}

// ---------------- RMSNorm rows in place (fp32) + bf16 copy (MFMA input) ----------------
__global__ __launch_bounds__(256)
void rmsnorm_rows(float* __restrict__ X, const float* __restrict__ g,
                  __hip_bfloat16* __restrict__ Xb)
{
    const int lane = threadIdx.x & 63;
    const size_t row = (size_t)blockIdx.x * 4 + (threadIdx.x >> 6);
    float4 x = *(const float4*)&X[row*256 + lane*4];
    float ssq = fmaf(x.x, x.x, fmaf(x.y, x.y, fmaf(x.z, x.z, x.w * x.w)));
    #pragma unroll
    for (int o = 1; o < 64; o <<= 1) ssq += __shfl_xor(ssq, o, 64);
    const float r = 1.0f / sqrtf(ssq * (1.0f/256.0f) + 1e-5f);
    float4 gg = *(const float4*)&g[lane*4];
    float y0 = (x.x*r)*gg.x, y1 = (x.y*r)*gg.y, y2 = (x.z*r)*gg.z, y3 = (x.w*r)*gg.w;
    float4 y = {y0, y1, y2, y3};
    *(float4*)&X[row*256 + lane*4] = y;
    __hip_bfloat16 h0 = __float2bfloat16(y0), h1 = __float2bfloat16(y1);
    __hip_bfloat16 h2 = __float2bfloat16(y2), h3 = __float2bfloat16(y3);
    ushort4 p;
    p.x = *(unsigned short*)&h0; p.y = *(unsigned short*)&h1;
    p.z = *(unsigned short*)&h2; p.w = *(unsigned short*)&h3;
    ((ushort4*)Xb)[row*64 + lane] = p;
}

// ---------------- bf16 MFMA logits: Out[32768][4096] = fp32(clamp(Q @ K^T * 1/16)) ----
// m97 structure: 128x128 tile, BK=64, global_load_lds(16B) staging, 2 barriers/K-step.
// Swizzle (rule #21, both-sides): LDS dest linear; global SOURCE slot pre-permuted by
// the involution slot^=row&7; ds_read applies the same XOR -> conflict-free b128 reads.
// Epilogue: LDS-bounce -> coalesced dwordx4 stores; also emits Tmax[row][tileN].
__device__ __forceinline__ void load_lds16(const void* g, void* l) {
    __builtin_amdgcn_global_load_lds((const __attribute__((address_space(1))) unsigned int*)g,
                                     (__attribute__((address_space(3))) unsigned int*)l, 16, 0, 0);
}

__global__ __launch_bounds__(256, 2)
void mfma_logits(const __hip_bfloat16* __restrict__ Qb, const __hip_bfloat16* __restrict__ Kb,
                 float* __restrict__ Out, float* __restrict__ Tmax)
{
    // 33KB shared: staging A/B tiles during K-loop; epilogue fp32 bounce tile + Pmax.
    __shared__ __align__(16) char smem[33792];
    __hip_bfloat16* Asm = (__hip_bfloat16*)smem;            // [128 rows][64 k] bf16, 16KB
    __hip_bfloat16* Bsm = (__hip_bfloat16*)(smem + 16384);  // [128 rows][64 k] bf16, 16KB
    float*          Eps = (float*)smem;                     // [64 rows][128 cols] fp32, 32KB
    float*          Pmax = (float*)(smem + 32768);          // [128 rows][2 halves], 1KB

    const int t    = threadIdx.x;
    const int lane = t & 63;
    const int w    = t >> 6;
    const int wm = w >> 1, wn = w & 1;      // 2x2 wave grid of 64x64 quadrants
    const int mb = blockIdx.x * 128;
    const int nb = blockIdx.y * 128;

    // --- staging geometry: row = i*32 + (t>>3); within-row slot written at (t&7)
    // holds global slot (t&7)^((t>>3)&7)  [involution, row-local] ---
    const int grow   = t >> 3;                       // + i*32 per issue
    const int gslot  = (t & 7) ^ ((t >> 3) & 7);
    const __hip_bfloat16* gA = Qb + (size_t)(mb + grow) * 256 + gslot * 8;
    const __hip_bfloat16* gB = Kb + (size_t)(nb + grow) * 256 + gslot * 8;
    __hip_bfloat16* lA = &Asm[w * 512];              // + i*2048 per issue (bf16 elems)
    __hip_bfloat16* lB = &Bsm[w * 512];

    // --- fragment geometry (guide §3): fr = lane&15 row-in-16, kq = lane>>4 ---
    const int fr = lane & 15;
    const int kq = lane >> 4;
    const int rswz = lane & 7;                       // row&7 for all our fragment rows
    const int ra0 = (wm * 64 + fr) * 64;             // A base elem offset (row*64)
    const int rb0 = (wn * 64 + fr) * 64;

    f32x4 acc[4][4];
    #pragma unroll
    for (int mi = 0; mi < 4; ++mi)
        #pragma unroll
        for (int ni = 0; ni < 4; ++ni) {
            acc[mi][ni][0] = 0.f; acc[mi][ni][1] = 0.f;
            acc[mi][ni][2] = 0.f; acc[mi][ni][3] = 0.f;
        }

    for (int ks = 0; ks < 4; ++ks) {
        const int k0 = ks * 64;
        #pragma unroll
        for (int i = 0; i < 4; ++i) {
            load_lds16(gA + (size_t)i * 32 * 256 + k0, lA + i * 2048);
            load_lds16(gB + (size_t)i * 32 * 256 + k0, lB + i * 2048);
        }
        __syncthreads();   // compiler drains vmcnt(0) before s_barrier [m97 evidence]

        #pragma unroll
        for (int kh = 0; kh < 2; ++kh) {            // k = ks*64 + kh*32 (ascending ==
            bf16x8 af[4], bg[4];                    //  R4..R9 order -> bit-identical acc)
            #pragma unroll
            for (int mi = 0; mi < 4; ++mi)
                af[mi] = *(const bf16x8*)&Asm[ra0 + mi*16*64 + (((kh<<2) + kq) ^ rswz) * 8];
            #pragma unroll
            for (int ni = 0; ni < 4; ++ni)
                bg[ni] = *(const bf16x8*)&Bsm[rb0 + ni*16*64 + (((kh<<2) + kq) ^ rswz) * 8];
            #pragma unroll
            for (int mi = 0; mi < 4; ++mi)
                #pragma unroll
                for (int ni = 0; ni < 4; ++ni)
                    acc[mi][ni] = __builtin_amdgcn_mfma_f32_16x16x32_bf16(
                        af[mi], bg[ni], acc[mi][ni], 0, 0, 0);
        }
        __syncthreads();   // LDS reads done before next K-step overwrites / epilogue
    }

    // ---- per-row partial maxima from acc regs (row = wm*64+mi*16+(lane>>4)*4+j) ----
    #pragma unroll
    for (int mi = 0; mi < 4; ++mi)
        #pragma unroll
        for (int j = 0; j < 4; ++j) {
            float mx = fmaxf(fmaxf(acc[mi][0][j], acc[mi][1][j]),
                             fmaxf(acc[mi][2][j], acc[mi][3][j]));
            #pragma unroll
            for (int o = 1; o < 16; o <<= 1) mx = fmaxf(mx, __shfl_xor(mx, o, 64));
            if ((lane & 15) == 0)
                Pmax[(wm*64 + mi*16 + (lane>>4)*4 + j)*2 + wn] = mx;
        }

    // ---- epilogue: LDS bounce -> coalesced full-row dwordx4 stores ----
    // C/D layout: col = lane&15, row = (lane>>4)*4 + j  [guide §3, m89-verified]
    // Scale+clamp applied BEFORE the bounce, same ops/order as R5..R9 -> bit-identical.
    const int cr = (lane >> 4) * 4;
    const int cc = lane & 15;
    #pragma unroll
    for (int c = 0; c < 2; ++c) {                    // chunk: rows [c*64, c*64+64)
        if (wm == c) {
            #pragma unroll
            for (int mi = 0; mi < 4; ++mi)
                #pragma unroll
                for (int ni = 0; ni < 4; ++ni) {
                    const int lrow = mi*16 + cr;                  // 0..63 within chunk
                    const int lcol = wn*64 + ni*16 + cc;          // 0..127
                    #pragma unroll
                    for (int j = 0; j < 4; ++j) {
                        float v = acc[mi][ni][j] * 0.0625f;
                        v = fminf(fmaxf(v, -16.0f), 16.0f);
                        Eps[(lrow + j) * 128 + lcol] = v;
                    }
                }
        }
        __syncthreads();   // bounce tile (and, first pass, Pmax) complete
        #pragma unroll
        for (int it = 0; it < 8; ++it) {
            const int p   = it * 1024 + t * 4;       // linear word index in [64][128]
            const int row = p >> 7;
            const int col = p & 127;
            float4 v = *(const float4*)&Eps[p];
            *(float4*)&Out[(size_t)(mb + c*64 + row) * 4096 + nb + col] = v;
        }
        __syncthreads();   // chunk read done before next chunk overwrites
    }

    // ---- Tmax: combine halves; max is monotone under clamp(0.0625*x) so this equals
    // the max of the stored (clamped) values. Pmax fenced by the barriers above. ----
    if (t < 128) {
        float raw = fmaxf(Pmax[t*2], Pmax[t*2 + 1]);
        float v = raw * 0.0625f;
        v = fminf(fmaxf(v, -16.0f), 16.0f);
        Tmax[(size_t)(mb + t) * 32 + blockIdx.y] = v;
    }
}

// ---------------- FROZEN canonical fp32 dot (argmax determinism anchor) ----------------
// DO NOT change the summation structure in future rounds. R3..R9 PASSED with this
// exact sequence (0 argmax flips vs numpy on the fixed dataset) — keep bit-identical.
__device__ __forceinline__ float dot256_f32(const float* __restrict__ a, const float* __restrict__ b)
{
    float s0 = 0.f, s1 = 0.f, s2 = 0.f, s3 = 0.f;
    #pragma unroll 8
    for (int j = 0; j < 64; ++j) {
        float4 x = ((const float4*)a)[j];
        float4 y = ((const float4*)b)[j];
        s0 = fmaf(x.x, y.x, s0);
        s1 = fmaf(x.y, y.y, s1);
        s2 = fmaf(x.z, y.z, s2);
        s3 = fmaf(x.w, y.w, s3);
    }
    return (s0 + s1) + (s2 + s3);
}

// ---------------- refine (fast): Tmax-pruned candidate scan + frozen dots ----------------
// Identical to R8/R9 (passed). NOTE: Qf may alias the Zq output region — each block
// reads ONLY its own 4 rows and overwrites them at the END (z_q store data-depends on
// all qrow loads via the reduce), so no ordering hazard.
__global__ __launch_bounds__(256)
void refine_argmax_fast(const float* __restrict__ L, const float* __restrict__ Tmax,
                        const float* __restrict__ Qf, const float* __restrict__ Kf,
                        const float* __restrict__ Vf, float* __restrict__ OutIdx,
                        float* __restrict__ Zq, float* __restrict__ Zq2)
{
    __shared__ int cnt[4];
    __shared__ int list[4][256];
    const int lane = threadIdx.x & 63;
    const int w    = threadIdx.x >> 6;
    const size_t row = (size_t)blockIdx.x * 4 + w;

    // phase 1: row max from 32 tile maxima
    float tm = (lane < 32) ? Tmax[row * 32 + lane] : -INFINITY;
    float gmax = tm;
    #pragma unroll
    for (int o = 1; o < 64; o <<= 1) gmax = fmaxf(gmax, __shfl_xor(gmax, o, 64));
    const float thr = gmax - 0.5f;

    if (lane == 0) cnt[w] = 0;
    __syncthreads();   // unconditional: every thread reaches this

    // phase 2: scan ONLY candidate tiles (512B each, float2/lane coalesced)
    for (int tile = 0; tile < 32; ++tile) {
        const float tmt = __shfl(tm, tile, 64);
        if (tmt >= thr) {
            const float2 v2 = *(const float2*)&L[row * 4096 + tile * 128 + lane * 2];
            if (v2.x >= thr) {
                int slot = atomicAdd(&cnt[w], 1);
                if (slot < 256) list[w][slot] = tile*128 + lane*2;
            }
            if (v2.y >= thr) {
                int slot = atomicAdd(&cnt[w], 1);
                if (slot < 256) list[w][slot] = tile*128 + lane*2 + 1;
            }
        }
    }
    __syncthreads();   // unconditional

    // phase 3: one candidate per lane, all dots in ONE exec pass (unchanged from R4..R9)
    int m = cnt[w]; if (m > 256) m = 256;
    float bv = -INFINITY;
    int   bi = 0x7fffffff;
    const float* qrow = Qf + row * 256;
    for (int base = 0; base < m; base += 64) {
        const int ci = base + lane;
        if (ci < m) {
            const int c = list[w][ci];
            float rv = dot256_f32(qrow, Kf + (size_t)c * 256) * 0.0625f;
            if (rv > bv || (rv == bv && c < bi)) { bv = rv; bi = c; }
        }
    }
    #pragma unroll
    for (int o = 1; o < 64; o <<= 1) {
        float ov = __shfl_xor(bv, o, 64);
        int   oi = __shfl_xor(bi, o, 64);
        if (ov > bv || (ov == bv && oi < bi)) { bv = ov; bi = oi; }
    }

    if (bi < 0) bi = 0;
    if (bi > 4095) bi = 4095;

    if (lane == 0) OutIdx[row] = (float)bi;

    // z_q = z_q_2 = v[idx]; stores happen after all qrow reads (data dep through bi).
    float4 vv = ((const float4*)(Vf + (size_t)bi * 256))[lane];
    ((float4*)Zq)[row*64 + lane]  = vv;
    ((float4*)Zq2)[row*64 + lane] = vv;
}

extern "C" void kernel_launch(void* const* d_in, const int* in_sizes, int n_in,
                              void* d_out, int out_size, void* d_ws, size_t ws_size,
                              hipStream_t stream)
{
    (void)in_sizes; (void)n_in; (void)out_size;
    const float* hs = (const float*)d_in[0];
    const float* cb = (const float*)d_in[1];
    const float* wq = (const float*)d_in[2];
    const float* bq = (const float*)d_in[3];
    const float* wk = (const float*)d_in[4];
    const float* bk = (const float*)d_in[5];
    const float* wv = (const float*)d_in[6];
    const float* bv = (const float*)d_in[7];
    const float* gq = (const float*)d_in[8];
    const float* gk = (const float*)d_in[9];
    float* out = (float*)d_out;   // fp32: reference outputs are fp32/int32

    if (ws_size < 31457280u) return;  // need 30MB scratch

    // d_out layout (floats): logits @0 [32768*4096], idx @134217728 [32768],
    // z_q @134250496 [32768*256], z_q_2 @142639104 [32768*256].
    float* qf = out + 134250496ull;   // q lives in the z_q region until the FINAL refine store

    char* ws = (char*)d_ws;
    float* kf = (float*)ws;                                   //  4 MB: k raw -> k_norm (in place)
    float* vf = (float*)(ws + 4194304);                       //  4 MB: v
    __hip_bfloat16* qb = (__hip_bfloat16*)(ws + 8388608);     // 16 MB: q_norm bf16
    __hip_bfloat16* kb = (__hip_bfloat16*)(ws + 25165824);    //  2 MB: k_norm bf16
    float* tmax = (float*)(ws + 27262976);                    //  4 MB: per-tile row max

    gemm_xw256<<<dim3(32, 2),  256, 0, stream>>>(cb, wk, bk, kf);
    gemm_xw256<<<dim3(32, 2),  256, 0, stream>>>(cb, wv, bv, vf);
    gemm_xw256<<<dim3(256, 2), 256, 0, stream>>>(hs, wq, bq, qf);
    rmsnorm_rows<<<1024, 256, 0, stream>>>(kf, gk, kb);
    rmsnorm_rows<<<8192, 256, 0, stream>>>(qf, gq, qb);

    // --- INSTRUMENTATION: mfma_logits twice. Pass 2 rewrites bit-identical values to
    // the same addresses (idempotent, deterministic) and absorbs pass 1's dirty-L2
    // writeback, mirroring the R8 single-pass context. Delta(dur_us) vs R8 == cost of
    // one mfma_logits pass in context. ---
    mfma_logits<<<dim3(256, 32), 256, 0, stream>>>(qb, kb, out, tmax);
    mfma_logits<<<dim3(256, 32), 256, 0, stream>>>(qb, kb, out, tmax);

    refine_argmax_fast<<<8192, 256, 0, stream>>>(out, tmax, qf, kf, vf,
        out + 134217728ull,   // idx
        out + 134250496ull,   // z_q   (aliases qf by design)
        out + 142639104ull);  // z_q_2
}

// Round 11
// 551.804 us; speedup vs baseline: 1.4350x; 1.4350x over previous
//
#include <hip/hip_runtime.h>
#include <hip/hip_bf16.h>

// AttentionForQuantizer: q/k/v proj + RMSNorm + logits(32768x4096) + argmax + gather.
// R11: ledger complete (R9/R10 instrumentation): mfma~223us, refine~120-166us,
// front-end+overhead~180us. This round: mfma_logits occupancy + locality —
// __launch_bounds__(256,4) (cap VGPR<=128 -> 4 blocks/CU; LDS 33.8KB allows it) and
// XCD-chunked 1-D grid swizzle (each XCD owns a 32-row-tile band x all cols: its 2MB
// Q-band + 2MB K fit the 4MB per-XCD L2; bijective since 8192%8==0). Per-tile compute
// and stored bits identical to R8 (passed). refine/gemms/rmsnorm byte-identical to R8.
// NOTE: rocprof rows for state-dependent dispatches are replay artifacts (poisoned
// buffers -> candidate explosion in refine); trust the timed ledger.

#define NTOK 32768
#define NCODE 4096
#define DIM 256

typedef __bf16 bf16x8 __attribute__((ext_vector_type(8)));
typedef float f32x4 __attribute__((ext_vector_type(4)));

// ---------------- fp32 GEMM: Y[M][256] = X[M][256] @ W[256][256] + bias ----------------
// 128x128 tile per block, 256 threads, 8x8 per thread, BK=32.
__global__ __launch_bounds__(256, 2)
void gemm_xw256(const float* __restrict__ X, const float* __restrict__ W,
                const float* __restrict__ bias, float* __restrict__ Y)
{
    __shared__ __align__(16) float Xs[32][132];  // [kk][m], padded
    __shared__ __align__(16) float Ws[32][132];  // [kk][n], padded
    const int t  = threadIdx.x;
    const int tm = t >> 4;         // 0..15
    const int tn = t & 15;         // 0..15
    const int mb = blockIdx.x * 128;
    const int nb = blockIdx.y * 128;

    float acc[8][8];
    #pragma unroll
    for (int i = 0; i < 8; ++i)
        #pragma unroll
        for (int j = 0; j < 8; ++j) acc[i][j] = 0.f;

    const int sxm = t >> 1;          // X staging: row 0..127
    const int sxh = (t & 1) * 16;    // X staging: k-half base
    const int swk = t >> 3;          // W staging: kk 0..31
    const int swc = (t & 7) * 16;    // W staging: col base

    for (int kb = 0; kb < 256; kb += 32) {
        float4 xv[4], wv[4];
        #pragma unroll
        for (int i = 0; i < 4; ++i) {
            xv[i] = *(const float4*)&X[(size_t)(mb + sxm) * 256 + kb + sxh + 4 * i];
            wv[i] = *(const float4*)&W[(size_t)(kb + swk) * 256 + nb + swc + 4 * i];
        }
        __syncthreads();  // previous iteration's LDS reads done before overwrite
        #pragma unroll
        for (int i = 0; i < 4; ++i) {
            Xs[sxh + 4*i + 0][sxm] = xv[i].x;
            Xs[sxh + 4*i + 1][sxm] = xv[i].y;
            Xs[sxh + 4*i + 2][sxm] = xv[i].z;
            Xs[sxh + 4*i + 3][sxm] = xv[i].w;
            *(float4*)&Ws[swk][swc + 4*i] = wv[i];
        }
        __syncthreads();
        #pragma unroll 8
        for (int kk = 0; kk < 32; ++kk) {
            float4 a0 = *(const float4*)&Xs[kk][tm*8];
            float4 a1 = *(const float4*)&Xs[kk][tm*8 + 4];
            float4 b0 = *(const float4*)&Ws[kk][tn*8];
            float4 b1 = *(const float4*)&Ws[kk][tn*8 + 4];
            float av[8] = {a0.x,a0.y,a0.z,a0.w,a1.x,a1.y,a1.z,a1.w};
            float bw[8] = {b0.x,b0.y,b0.z,b0.w,b1.x,b1.y,b1.z,b1.w};
            #pragma unroll
            for (int i = 0; i < 8; ++i)
                #pragma unroll
                for (int j = 0; j < 8; ++j)
                    acc[i][j] = fmaf(av[i], bw[j], acc[i][j]);
        }
    }

    float4 bb0 = *(const float4*)&bias[nb + tn*8];
    float4 bb1 = *(const float4*)&bias[nb + tn*8 + 4];
    float bb[8] = {bb0.x,bb0.y,bb0.z,bb0.w,bb1.x,bb1.y,bb1.z,bb1.w};
    #pragma unroll
    for (int i = 0; i < 8; ++i) {
        const size_t row = (size_t)(mb + tm*8 + i);
        float4 o0 = {acc[i][0]+bb[0], acc[i][1]+bb[1], acc[i][2]+bb[2], acc[i][3]+bb[3]};
        float4 o1 = {acc[i][4]+bb[4], acc[i][5]+bb[5], acc[i][6]+bb[6], acc[i][7]+bb[7]};
        *(float4*)&Y[row*256 + nb + tn*8]     = o0;
        *(float4*)&Y[row*256 + nb + tn*8 + 4] = o1;
    }
}

// ---------------- RMSNorm rows in place (fp32) + bf16 copy (MFMA input) ----------------
__global__ __launch_bounds__(256)
void rmsnorm_rows(float* __restrict__ X, const float* __restrict__ g,
                  __hip_bfloat16* __restrict__ Xb)
{
    const int lane = threadIdx.x & 63;
    const size_t row = (size_t)blockIdx.x * 4 + (threadIdx.x >> 6);
    float4 x = *(const float4*)&X[row*256 + lane*4];
    float ssq = fmaf(x.x, x.x, fmaf(x.y, x.y, fmaf(x.z, x.z, x.w * x.w)));
    #pragma unroll
    for (int o = 1; o < 64; o <<= 1) ssq += __shfl_xor(ssq, o, 64);
    const float r = 1.0f / sqrtf(ssq * (1.0f/256.0f) + 1e-5f);
    float4 gg = *(const float4*)&g[lane*4];
    float y0 = (x.x*r)*gg.x, y1 = (x.y*r)*gg.y, y2 = (x.z*r)*gg.z, y3 = (x.w*r)*gg.w;
    float4 y = {y0, y1, y2, y3};
    *(float4*)&X[row*256 + lane*4] = y;
    __hip_bfloat16 h0 = __float2bfloat16(y0), h1 = __float2bfloat16(y1);
    __hip_bfloat16 h2 = __float2bfloat16(y2), h3 = __float2bfloat16(y3);
    ushort4 p;
    p.x = *(unsigned short*)&h0; p.y = *(unsigned short*)&h1;
    p.z = *(unsigned short*)&h2; p.w = *(unsigned short*)&h3;
    ((ushort4*)Xb)[row*64 + lane] = p;
}

// ---------------- bf16 MFMA logits: Out[32768][4096] = fp32(clamp(Q @ K^T * 1/16)) ----
// m97 structure: 128x128 tile, BK=64, global_load_lds(16B) staging, 2 barriers/K-step.
// Swizzle (rule #21, both-sides): LDS dest linear; global SOURCE slot pre-permuted by
// the involution slot^=row&7; ds_read applies the same XOR -> conflict-free b128 reads.
// R11: __launch_bounds__(256,4) (VGPR<=128 -> 4 blocks/CU) + XCD-chunked grid swizzle
// (per-XCD 2MB Q-band + 2MB K -> L2-resident). Per-tile values bit-identical to R8.
__device__ __forceinline__ void load_lds16(const void* g, void* l) {
    __builtin_amdgcn_global_load_lds((const __attribute__((address_space(1))) unsigned int*)g,
                                     (__attribute__((address_space(3))) unsigned int*)l, 16, 0, 0);
}

__global__ __launch_bounds__(256, 4)
void mfma_logits(const __hip_bfloat16* __restrict__ Qb, const __hip_bfloat16* __restrict__ Kb,
                 float* __restrict__ Out, float* __restrict__ Tmax)
{
    // 33KB shared: staging A/B tiles during K-loop; epilogue fp32 bounce tile + Pmax.
    __shared__ __align__(16) char smem[33792];
    __hip_bfloat16* Asm = (__hip_bfloat16*)smem;            // [128 rows][64 k] bf16, 16KB
    __hip_bfloat16* Bsm = (__hip_bfloat16*)(smem + 16384);  // [128 rows][64 k] bf16, 16KB
    float*          Eps = (float*)smem;                     // [64 rows][128 cols] fp32, 32KB
    float*          Pmax = (float*)(smem + 32768);          // [128 rows][2 halves], 1KB

    const int t    = threadIdx.x;
    const int lane = t & 63;
    const int w    = t >> 6;
    const int wm = w >> 1, wn = w & 1;      // 2x2 wave grid of 64x64 quadrants

    // --- XCD-chunked swizzle (bijective: 8192 = 8 XCDs x 32 row-tiles x 32 col-tiles).
    // Each XCD owns a contiguous 32-row-tile band across all 32 col-tiles: per-XCD
    // working set = 2MB Q-band + 2MB K <= 4MB L2. ---
    const int bid = blockIdx.x;
    const int xcd = bid & 7;
    const int cid = bid >> 3;                // 0..1023
    const int mb  = (xcd * 32 + (cid & 31)) * 128;
    const int ctl = cid >> 5;                // col-tile 0..31
    const int nb  = ctl * 128;

    // --- staging geometry: row = i*32 + (t>>3); within-row slot written at (t&7)
    // holds global slot (t&7)^((t>>3)&7)  [involution, row-local] ---
    const int grow   = t >> 3;                       // + i*32 per issue
    const int gslot  = (t & 7) ^ ((t >> 3) & 7);
    const __hip_bfloat16* gA = Qb + (size_t)(mb + grow) * 256 + gslot * 8;
    const __hip_bfloat16* gB = Kb + (size_t)(nb + grow) * 256 + gslot * 8;
    __hip_bfloat16* lA = &Asm[w * 512];              // + i*2048 per issue (bf16 elems)
    __hip_bfloat16* lB = &Bsm[w * 512];

    // --- fragment geometry (guide §3): fr = lane&15 row-in-16, kq = lane>>4 ---
    const int fr = lane & 15;
    const int kq = lane >> 4;
    const int rswz = lane & 7;                       // row&7 for all our fragment rows
    const int ra0 = (wm * 64 + fr) * 64;             // A base elem offset (row*64)
    const int rb0 = (wn * 64 + fr) * 64;

    f32x4 acc[4][4];
    #pragma unroll
    for (int mi = 0; mi < 4; ++mi)
        #pragma unroll
        for (int ni = 0; ni < 4; ++ni) {
            acc[mi][ni][0] = 0.f; acc[mi][ni][1] = 0.f;
            acc[mi][ni][2] = 0.f; acc[mi][ni][3] = 0.f;
        }

    for (int ks = 0; ks < 4; ++ks) {
        const int k0 = ks * 64;
        #pragma unroll
        for (int i = 0; i < 4; ++i) {
            load_lds16(gA + (size_t)i * 32 * 256 + k0, lA + i * 2048);
            load_lds16(gB + (size_t)i * 32 * 256 + k0, lB + i * 2048);
        }
        __syncthreads();   // compiler drains vmcnt(0) before s_barrier [m97 evidence]

        #pragma unroll
        for (int kh = 0; kh < 2; ++kh) {            // k = ks*64 + kh*32 (ascending ==
            bf16x8 af[4], bg[4];                    //  R4..R10 order -> bit-identical acc)
            #pragma unroll
            for (int mi = 0; mi < 4; ++mi)
                af[mi] = *(const bf16x8*)&Asm[ra0 + mi*16*64 + (((kh<<2) + kq) ^ rswz) * 8];
            #pragma unroll
            for (int ni = 0; ni < 4; ++ni)
                bg[ni] = *(const bf16x8*)&Bsm[rb0 + ni*16*64 + (((kh<<2) + kq) ^ rswz) * 8];
            #pragma unroll
            for (int mi = 0; mi < 4; ++mi)
                #pragma unroll
                for (int ni = 0; ni < 4; ++ni)
                    acc[mi][ni] = __builtin_amdgcn_mfma_f32_16x16x32_bf16(
                        af[mi], bg[ni], acc[mi][ni], 0, 0, 0);
        }
        __syncthreads();   // LDS reads done before next K-step overwrites / epilogue
    }

    // ---- per-row partial maxima from acc regs (row = wm*64+mi*16+(lane>>4)*4+j) ----
    #pragma unroll
    for (int mi = 0; mi < 4; ++mi)
        #pragma unroll
        for (int j = 0; j < 4; ++j) {
            float mx = fmaxf(fmaxf(acc[mi][0][j], acc[mi][1][j]),
                             fmaxf(acc[mi][2][j], acc[mi][3][j]));
            #pragma unroll
            for (int o = 1; o < 16; o <<= 1) mx = fmaxf(mx, __shfl_xor(mx, o, 64));
            if ((lane & 15) == 0)
                Pmax[(wm*64 + mi*16 + (lane>>4)*4 + j)*2 + wn] = mx;
        }

    // ---- epilogue: LDS bounce -> coalesced full-row dwordx4 stores ----
    // C/D layout: col = lane&15, row = (lane>>4)*4 + j  [guide §3, m89-verified]
    // Scale+clamp applied BEFORE the bounce, same ops/order as R5..R10 -> bit-identical.
    const int cr = (lane >> 4) * 4;
    const int cc = lane & 15;
    #pragma unroll
    for (int c = 0; c < 2; ++c) {                    // chunk: rows [c*64, c*64+64)
        if (wm == c) {
            #pragma unroll
            for (int mi = 0; mi < 4; ++mi)
                #pragma unroll
                for (int ni = 0; ni < 4; ++ni) {
                    const int lrow = mi*16 + cr;                  // 0..63 within chunk
                    const int lcol = wn*64 + ni*16 + cc;          // 0..127
                    #pragma unroll
                    for (int j = 0; j < 4; ++j) {
                        float v = acc[mi][ni][j] * 0.0625f;
                        v = fminf(fmaxf(v, -16.0f), 16.0f);
                        Eps[(lrow + j) * 128 + lcol] = v;
                    }
                }
        }
        __syncthreads();   // bounce tile (and, first pass, Pmax) complete
        #pragma unroll
        for (int it = 0; it < 8; ++it) {
            const int p   = it * 1024 + t * 4;       // linear word index in [64][128]
            const int row = p >> 7;
            const int col = p & 127;
            float4 v = *(const float4*)&Eps[p];
            *(float4*)&Out[(size_t)(mb + c*64 + row) * 4096 + nb + col] = v;
        }
        __syncthreads();   // chunk read done before next chunk overwrites
    }

    // ---- Tmax: combine halves; max is monotone under clamp(0.0625*x) so this equals
    // the max of the stored (clamped) values. Pmax fenced by the barriers above. ----
    if (t < 128) {
        float raw = fmaxf(Pmax[t*2], Pmax[t*2 + 1]);
        float v = raw * 0.0625f;
        v = fminf(fmaxf(v, -16.0f), 16.0f);
        Tmax[(size_t)(mb + t) * 32 + ctl] = v;
    }
}

// ---------------- FROZEN canonical fp32 dot (argmax determinism anchor) ----------------
// DO NOT change the summation structure in future rounds. R3..R10 PASSED with this
// exact sequence (0 argmax flips vs numpy on the fixed dataset) — keep bit-identical.
__device__ __forceinline__ float dot256_f32(const float* __restrict__ a, const float* __restrict__ b)
{
    float s0 = 0.f, s1 = 0.f, s2 = 0.f, s3 = 0.f;
    #pragma unroll 8
    for (int j = 0; j < 64; ++j) {
        float4 x = ((const float4*)a)[j];
        float4 y = ((const float4*)b)[j];
        s0 = fmaf(x.x, y.x, s0);
        s1 = fmaf(x.y, y.y, s1);
        s2 = fmaf(x.z, y.z, s2);
        s3 = fmaf(x.w, y.w, s3);
    }
    return (s0 + s1) + (s2 + s3);
}

// ---------------- refine (fast): Tmax-pruned candidate scan + frozen dots ----------------
// Identical to R8..R10 (passed). NOTE: Qf may alias the Zq output region — each block
// reads ONLY its own 4 rows and overwrites them at the END (z_q store data-depends on
// all qrow loads via the reduce), so no ordering hazard.
__global__ __launch_bounds__(256)
void refine_argmax_fast(const float* __restrict__ L, const float* __restrict__ Tmax,
                        const float* __restrict__ Qf, const float* __restrict__ Kf,
                        const float* __restrict__ Vf, float* __restrict__ OutIdx,
                        float* __restrict__ Zq, float* __restrict__ Zq2)
{
    __shared__ int cnt[4];
    __shared__ int list[4][256];
    const int lane = threadIdx.x & 63;
    const int w    = threadIdx.x >> 6;
    const size_t row = (size_t)blockIdx.x * 4 + w;

    // phase 1: row max from 32 tile maxima
    float tm = (lane < 32) ? Tmax[row * 32 + lane] : -INFINITY;
    float gmax = tm;
    #pragma unroll
    for (int o = 1; o < 64; o <<= 1) gmax = fmaxf(gmax, __shfl_xor(gmax, o, 64));
    const float thr = gmax - 0.5f;

    if (lane == 0) cnt[w] = 0;
    __syncthreads();   // unconditional: every thread reaches this

    // phase 2: scan ONLY candidate tiles (512B each, float2/lane coalesced)
    for (int tile = 0; tile < 32; ++tile) {
        const float tmt = __shfl(tm, tile, 64);
        if (tmt >= thr) {
            const float2 v2 = *(const float2*)&L[row * 4096 + tile * 128 + lane * 2];
            if (v2.x >= thr) {
                int slot = atomicAdd(&cnt[w], 1);
                if (slot < 256) list[w][slot] = tile*128 + lane*2;
            }
            if (v2.y >= thr) {
                int slot = atomicAdd(&cnt[w], 1);
                if (slot < 256) list[w][slot] = tile*128 + lane*2 + 1;
            }
        }
    }
    __syncthreads();   // unconditional

    // phase 3: one candidate per lane, all dots in ONE exec pass (unchanged from R4..R10)
    int m = cnt[w]; if (m > 256) m = 256;
    float bv = -INFINITY;
    int   bi = 0x7fffffff;
    const float* qrow = Qf + row * 256;
    for (int base = 0; base < m; base += 64) {
        const int ci = base + lane;
        if (ci < m) {
            const int c = list[w][ci];
            float rv = dot256_f32(qrow, Kf + (size_t)c * 256) * 0.0625f;
            if (rv > bv || (rv == bv && c < bi)) { bv = rv; bi = c; }
        }
    }
    #pragma unroll
    for (int o = 1; o < 64; o <<= 1) {
        float ov = __shfl_xor(bv, o, 64);
        int   oi = __shfl_xor(bi, o, 64);
        if (ov > bv || (ov == bv && oi < bi)) { bv = ov; bi = oi; }
    }

    if (bi < 0) bi = 0;
    if (bi > 4095) bi = 4095;

    if (lane == 0) OutIdx[row] = (float)bi;

    // z_q = z_q_2 = v[idx]; stores happen after all qrow reads (data dep through bi).
    float4 vv = ((const float4*)(Vf + (size_t)bi * 256))[lane];
    ((float4*)Zq)[row*64 + lane]  = vv;
    ((float4*)Zq2)[row*64 + lane] = vv;
}

extern "C" void kernel_launch(void* const* d_in, const int* in_sizes, int n_in,
                              void* d_out, int out_size, void* d_ws, size_t ws_size,
                              hipStream_t stream)
{
    (void)in_sizes; (void)n_in; (void)out_size;
    const float* hs = (const float*)d_in[0];
    const float* cb = (const float*)d_in[1];
    const float* wq = (const float*)d_in[2];
    const float* bq = (const float*)d_in[3];
    const float* wk = (const float*)d_in[4];
    const float* bk = (const float*)d_in[5];
    const float* wv = (const float*)d_in[6];
    const float* bv = (const float*)d_in[7];
    const float* gq = (const float*)d_in[8];
    const float* gk = (const float*)d_in[9];
    float* out = (float*)d_out;   // fp32: reference outputs are fp32/int32

    if (ws_size < 31457280u) return;  // need 30MB scratch

    // d_out layout (floats): logits @0 [32768*4096], idx @134217728 [32768],
    // z_q @134250496 [32768*256], z_q_2 @142639104 [32768*256].
    float* qf = out + 134250496ull;   // q lives in the z_q region until the FINAL refine store

    char* ws = (char*)d_ws;
    float* kf = (float*)ws;                                   //  4 MB: k raw -> k_norm (in place)
    float* vf = (float*)(ws + 4194304);                       //  4 MB: v
    __hip_bfloat16* qb = (__hip_bfloat16*)(ws + 8388608);     // 16 MB: q_norm bf16
    __hip_bfloat16* kb = (__hip_bfloat16*)(ws + 25165824);    //  2 MB: k_norm bf16
    float* tmax = (float*)(ws + 27262976);                    //  4 MB: per-tile row max

    gemm_xw256<<<dim3(32, 2),  256, 0, stream>>>(cb, wk, bk, kf);
    gemm_xw256<<<dim3(32, 2),  256, 0, stream>>>(cb, wv, bv, vf);
    gemm_xw256<<<dim3(256, 2), 256, 0, stream>>>(hs, wq, bq, qf);
    rmsnorm_rows<<<1024, 256, 0, stream>>>(kf, gk, kb);
    rmsnorm_rows<<<8192, 256, 0, stream>>>(qf, gq, qb);
    mfma_logits<<<8192, 256, 0, stream>>>(qb, kb, out, tmax);
    refine_argmax_fast<<<8192, 256, 0, stream>>>(out, tmax, qf, kf, vf,
        out + 134217728ull,   // idx
        out + 134250496ull,   // z_q   (aliases qf by design)
        out + 142639104ull);  // z_q_2
}

// Round 12
// 484.177 us; speedup vs baseline: 1.6355x; 1.1397x over previous
//
#include <hip/hip_runtime.h>
#include <hip/hip_bf16.h>

// AttentionForQuantizer: q/k/v proj + RMSNorm + logits(32768x4096) + argmax + gather.
// R12: DISPATCH FUSION (7 -> 4 kernels). Three nulls (R7/R8 traffic cut, R11
// occupancy+swizzle) + a ~100us unattributed ledger residual point at per-dispatch
// graph overhead G inflating every measurement. The 3 projection GEMMs fuse into one
// kernel (block-range branch, identical body -> identical FMA order -> bit-identical
// outputs); the 2 rmsnorms fuse likewise. mfma_logits/refine byte-identical to R11
// (passed). This is simultaneously a likely win and a direct measurement of G:
//   total ~430-460 => G~30-40/node (continue consolidating);
//   total ~525-545 => G small, per-kernel work is real (restructure mfma next).

#define NTOK 32768
#define NCODE 4096
#define DIM 256

typedef __bf16 bf16x8 __attribute__((ext_vector_type(8)));
typedef float f32x4 __attribute__((ext_vector_type(4)));

// ---------------- fused fp32 GEMMs: k, v, q projections in one dispatch ----------------
// Body identical to R3..R11 gemm_xw256 (same FMA order -> bit-identical results).
// Grid (320, 2): bx<32 -> k-proj, bx<64 -> v-proj, else q-proj (mb = (bx-64)*128).
__global__ __launch_bounds__(256, 2)
void gemm_fused(const float* __restrict__ hs, const float* __restrict__ cb,
                const float* __restrict__ wq, const float* __restrict__ bq,
                const float* __restrict__ wk, const float* __restrict__ bk,
                const float* __restrict__ wv, const float* __restrict__ bv,
                float* __restrict__ qf, float* __restrict__ kf, float* __restrict__ vf)
{
    __shared__ __align__(16) float Xs[32][132];  // [kk][m], padded
    __shared__ __align__(16) float Ws[32][132];  // [kk][n], padded
    const int t  = threadIdx.x;
    const int tm = t >> 4;         // 0..15
    const int tn = t & 15;         // 0..15

    const int bx = blockIdx.x;
    const float* X; const float* W; const float* bias; float* Y; int mb;
    if (bx < 32)      { X = cb; W = wk; bias = bk; Y = kf; mb = bx * 128; }
    else if (bx < 64) { X = cb; W = wv; bias = bv; Y = vf; mb = (bx - 32) * 128; }
    else              { X = hs; W = wq; bias = bq; Y = qf; mb = (bx - 64) * 128; }
    const int nb = blockIdx.y * 128;

    float acc[8][8];
    #pragma unroll
    for (int i = 0; i < 8; ++i)
        #pragma unroll
        for (int j = 0; j < 8; ++j) acc[i][j] = 0.f;

    const int sxm = t >> 1;          // X staging: row 0..127
    const int sxh = (t & 1) * 16;    // X staging: k-half base
    const int swk = t >> 3;          // W staging: kk 0..31
    const int swc = (t & 7) * 16;    // W staging: col base

    for (int kb = 0; kb < 256; kb += 32) {
        float4 xv[4], wv4[4];
        #pragma unroll
        for (int i = 0; i < 4; ++i) {
            xv[i]  = *(const float4*)&X[(size_t)(mb + sxm) * 256 + kb + sxh + 4 * i];
            wv4[i] = *(const float4*)&W[(size_t)(kb + swk) * 256 + nb + swc + 4 * i];
        }
        __syncthreads();  // previous iteration's LDS reads done before overwrite
        #pragma unroll
        for (int i = 0; i < 4; ++i) {
            Xs[sxh + 4*i + 0][sxm] = xv[i].x;
            Xs[sxh + 4*i + 1][sxm] = xv[i].y;
            Xs[sxh + 4*i + 2][sxm] = xv[i].z;
            Xs[sxh + 4*i + 3][sxm] = xv[i].w;
            *(float4*)&Ws[swk][swc + 4*i] = wv4[i];
        }
        __syncthreads();
        #pragma unroll 8
        for (int kk = 0; kk < 32; ++kk) {
            float4 a0 = *(const float4*)&Xs[kk][tm*8];
            float4 a1 = *(const float4*)&Xs[kk][tm*8 + 4];
            float4 b0 = *(const float4*)&Ws[kk][tn*8];
            float4 b1 = *(const float4*)&Ws[kk][tn*8 + 4];
            float av[8] = {a0.x,a0.y,a0.z,a0.w,a1.x,a1.y,a1.z,a1.w};
            float bw[8] = {b0.x,b0.y,b0.z,b0.w,b1.x,b1.y,b1.z,b1.w};
            #pragma unroll
            for (int i = 0; i < 8; ++i)
                #pragma unroll
                for (int j = 0; j < 8; ++j)
                    acc[i][j] = fmaf(av[i], bw[j], acc[i][j]);
        }
    }

    float4 bb0 = *(const float4*)&bias[nb + tn*8];
    float4 bb1 = *(const float4*)&bias[nb + tn*8 + 4];
    float bb[8] = {bb0.x,bb0.y,bb0.z,bb0.w,bb1.x,bb1.y,bb1.z,bb1.w};
    #pragma unroll
    for (int i = 0; i < 8; ++i) {
        const size_t row = (size_t)(mb + tm*8 + i);
        float4 o0 = {acc[i][0]+bb[0], acc[i][1]+bb[1], acc[i][2]+bb[2], acc[i][3]+bb[3]};
        float4 o1 = {acc[i][4]+bb[4], acc[i][5]+bb[5], acc[i][6]+bb[6], acc[i][7]+bb[7]};
        *(float4*)&Y[row*256 + nb + tn*8]     = o0;
        *(float4*)&Y[row*256 + nb + tn*8 + 4] = o1;
    }
}

// ---------------- fused RMSNorm: k rows + q rows in one dispatch ----------------
// Body identical to R3..R11 rmsnorm_rows (same ops per row -> bit-identical).
// Grid 9216: b<1024 -> k (4096 rows), else q (32768 rows).
__global__ __launch_bounds__(256)
void rmsnorm_fused(float* __restrict__ kf, float* __restrict__ qf,
                   const float* __restrict__ gk, const float* __restrict__ gq,
                   __hip_bfloat16* __restrict__ kb, __hip_bfloat16* __restrict__ qb)
{
    const int b = blockIdx.x;
    float* X; const float* g; __hip_bfloat16* Xb; size_t row;
    if (b < 1024) { X = kf; g = gk; Xb = kb; row = (size_t)b * 4 + (threadIdx.x >> 6); }
    else { X = qf; g = gq; Xb = qb; row = (size_t)(b - 1024) * 4 + (threadIdx.x >> 6); }

    const int lane = threadIdx.x & 63;
    float4 x = *(const float4*)&X[row*256 + lane*4];
    float ssq = fmaf(x.x, x.x, fmaf(x.y, x.y, fmaf(x.z, x.z, x.w * x.w)));
    #pragma unroll
    for (int o = 1; o < 64; o <<= 1) ssq += __shfl_xor(ssq, o, 64);
    const float r = 1.0f / sqrtf(ssq * (1.0f/256.0f) + 1e-5f);
    float4 gg = *(const float4*)&g[lane*4];
    float y0 = (x.x*r)*gg.x, y1 = (x.y*r)*gg.y, y2 = (x.z*r)*gg.z, y3 = (x.w*r)*gg.w;
    float4 y = {y0, y1, y2, y3};
    *(float4*)&X[row*256 + lane*4] = y;
    __hip_bfloat16 h0 = __float2bfloat16(y0), h1 = __float2bfloat16(y1);
    __hip_bfloat16 h2 = __float2bfloat16(y2), h3 = __float2bfloat16(y3);
    ushort4 p;
    p.x = *(unsigned short*)&h0; p.y = *(unsigned short*)&h1;
    p.z = *(unsigned short*)&h2; p.w = *(unsigned short*)&h3;
    ((ushort4*)Xb)[row*64 + lane] = p;
}

// ---------------- bf16 MFMA logits: Out[32768][4096] = fp32(clamp(Q @ K^T * 1/16)) ----
// Byte-identical to R11 (passed): m97 structure, both-sides LDS swizzle, LDS-bounce
// epilogue, Tmax emission, __launch_bounds__(256,4), XCD-chunked grid swizzle.
__device__ __forceinline__ void load_lds16(const void* g, void* l) {
    __builtin_amdgcn_global_load_lds((const __attribute__((address_space(1))) unsigned int*)g,
                                     (__attribute__((address_space(3))) unsigned int*)l, 16, 0, 0);
}

__global__ __launch_bounds__(256, 4)
void mfma_logits(const __hip_bfloat16* __restrict__ Qb, const __hip_bfloat16* __restrict__ Kb,
                 float* __restrict__ Out, float* __restrict__ Tmax)
{
    __shared__ __align__(16) char smem[33792];
    __hip_bfloat16* Asm = (__hip_bfloat16*)smem;            // [128 rows][64 k] bf16, 16KB
    __hip_bfloat16* Bsm = (__hip_bfloat16*)(smem + 16384);  // [128 rows][64 k] bf16, 16KB
    float*          Eps = (float*)smem;                     // [64 rows][128 cols] fp32, 32KB
    float*          Pmax = (float*)(smem + 32768);          // [128 rows][2 halves], 1KB

    const int t    = threadIdx.x;
    const int lane = t & 63;
    const int w    = t >> 6;
    const int wm = w >> 1, wn = w & 1;      // 2x2 wave grid of 64x64 quadrants

    const int bid = blockIdx.x;
    const int xcd = bid & 7;
    const int cid = bid >> 3;                // 0..1023
    const int mb  = (xcd * 32 + (cid & 31)) * 128;
    const int ctl = cid >> 5;                // col-tile 0..31
    const int nb  = ctl * 128;

    const int grow   = t >> 3;                       // + i*32 per issue
    const int gslot  = (t & 7) ^ ((t >> 3) & 7);
    const __hip_bfloat16* gA = Qb + (size_t)(mb + grow) * 256 + gslot * 8;
    const __hip_bfloat16* gB = Kb + (size_t)(nb + grow) * 256 + gslot * 8;
    __hip_bfloat16* lA = &Asm[w * 512];              // + i*2048 per issue (bf16 elems)
    __hip_bfloat16* lB = &Bsm[w * 512];

    const int fr = lane & 15;
    const int kq = lane >> 4;
    const int rswz = lane & 7;                       // row&7 for all our fragment rows
    const int ra0 = (wm * 64 + fr) * 64;             // A base elem offset (row*64)
    const int rb0 = (wn * 64 + fr) * 64;

    f32x4 acc[4][4];
    #pragma unroll
    for (int mi = 0; mi < 4; ++mi)
        #pragma unroll
        for (int ni = 0; ni < 4; ++ni) {
            acc[mi][ni][0] = 0.f; acc[mi][ni][1] = 0.f;
            acc[mi][ni][2] = 0.f; acc[mi][ni][3] = 0.f;
        }

    for (int ks = 0; ks < 4; ++ks) {
        const int k0 = ks * 64;
        #pragma unroll
        for (int i = 0; i < 4; ++i) {
            load_lds16(gA + (size_t)i * 32 * 256 + k0, lA + i * 2048);
            load_lds16(gB + (size_t)i * 32 * 256 + k0, lB + i * 2048);
        }
        __syncthreads();   // compiler drains vmcnt(0) before s_barrier [m97 evidence]

        #pragma unroll
        for (int kh = 0; kh < 2; ++kh) {            // ascending k == R4..R11 order
            bf16x8 af[4], bg[4];
            #pragma unroll
            for (int mi = 0; mi < 4; ++mi)
                af[mi] = *(const bf16x8*)&Asm[ra0 + mi*16*64 + (((kh<<2) + kq) ^ rswz) * 8];
            #pragma unroll
            for (int ni = 0; ni < 4; ++ni)
                bg[ni] = *(const bf16x8*)&Bsm[rb0 + ni*16*64 + (((kh<<2) + kq) ^ rswz) * 8];
            #pragma unroll
            for (int mi = 0; mi < 4; ++mi)
                #pragma unroll
                for (int ni = 0; ni < 4; ++ni)
                    acc[mi][ni] = __builtin_amdgcn_mfma_f32_16x16x32_bf16(
                        af[mi], bg[ni], acc[mi][ni], 0, 0, 0);
        }
        __syncthreads();   // LDS reads done before next K-step overwrites / epilogue
    }

    // ---- per-row partial maxima from acc regs (row = wm*64+mi*16+(lane>>4)*4+j) ----
    #pragma unroll
    for (int mi = 0; mi < 4; ++mi)
        #pragma unroll
        for (int j = 0; j < 4; ++j) {
            float mx = fmaxf(fmaxf(acc[mi][0][j], acc[mi][1][j]),
                             fmaxf(acc[mi][2][j], acc[mi][3][j]));
            #pragma unroll
            for (int o = 1; o < 16; o <<= 1) mx = fmaxf(mx, __shfl_xor(mx, o, 64));
            if ((lane & 15) == 0)
                Pmax[(wm*64 + mi*16 + (lane>>4)*4 + j)*2 + wn] = mx;
        }

    // ---- epilogue: LDS bounce -> coalesced full-row dwordx4 stores ----
    const int cr = (lane >> 4) * 4;
    const int cc = lane & 15;
    #pragma unroll
    for (int c = 0; c < 2; ++c) {                    // chunk: rows [c*64, c*64+64)
        if (wm == c) {
            #pragma unroll
            for (int mi = 0; mi < 4; ++mi)
                #pragma unroll
                for (int ni = 0; ni < 4; ++ni) {
                    const int lrow = mi*16 + cr;                  // 0..63 within chunk
                    const int lcol = wn*64 + ni*16 + cc;          // 0..127
                    #pragma unroll
                    for (int j = 0; j < 4; ++j) {
                        float v = acc[mi][ni][j] * 0.0625f;
                        v = fminf(fmaxf(v, -16.0f), 16.0f);
                        Eps[(lrow + j) * 128 + lcol] = v;
                    }
                }
        }
        __syncthreads();   // bounce tile (and, first pass, Pmax) complete
        #pragma unroll
        for (int it = 0; it < 8; ++it) {
            const int p   = it * 1024 + t * 4;       // linear word index in [64][128]
            const int row = p >> 7;
            const int col = p & 127;
            float4 v = *(const float4*)&Eps[p];
            *(float4*)&Out[(size_t)(mb + c*64 + row) * 4096 + nb + col] = v;
        }
        __syncthreads();   // chunk read done before next chunk overwrites
    }

    // ---- Tmax: max is monotone under clamp(0.0625*x) -> equals max of stored values.
    if (t < 128) {
        float raw = fmaxf(Pmax[t*2], Pmax[t*2 + 1]);
        float v = raw * 0.0625f;
        v = fminf(fmaxf(v, -16.0f), 16.0f);
        Tmax[(size_t)(mb + t) * 32 + ctl] = v;
    }
}

// ---------------- FROZEN canonical fp32 dot (argmax determinism anchor) ----------------
// DO NOT change the summation structure in future rounds. R3..R11 PASSED with this
// exact sequence (0 argmax flips vs numpy on the fixed dataset) — keep bit-identical.
__device__ __forceinline__ float dot256_f32(const float* __restrict__ a, const float* __restrict__ b)
{
    float s0 = 0.f, s1 = 0.f, s2 = 0.f, s3 = 0.f;
    #pragma unroll 8
    for (int j = 0; j < 64; ++j) {
        float4 x = ((const float4*)a)[j];
        float4 y = ((const float4*)b)[j];
        s0 = fmaf(x.x, y.x, s0);
        s1 = fmaf(x.y, y.y, s1);
        s2 = fmaf(x.z, y.z, s2);
        s3 = fmaf(x.w, y.w, s3);
    }
    return (s0 + s1) + (s2 + s3);
}

// ---------------- refine (fast): Tmax-pruned candidate scan + frozen dots ----------------
// Identical to R8..R11 (passed). Qf aliases the Zq output region — each block reads
// ONLY its own 4 rows and overwrites them at the END (data dep through bi).
__global__ __launch_bounds__(256)
void refine_argmax_fast(const float* __restrict__ L, const float* __restrict__ Tmax,
                        const float* __restrict__ Qf, const float* __restrict__ Kf,
                        const float* __restrict__ Vf, float* __restrict__ OutIdx,
                        float* __restrict__ Zq, float* __restrict__ Zq2)
{
    __shared__ int cnt[4];
    __shared__ int list[4][256];
    const int lane = threadIdx.x & 63;
    const int w    = threadIdx.x >> 6;
    const size_t row = (size_t)blockIdx.x * 4 + w;

    // phase 1: row max from 32 tile maxima
    float tm = (lane < 32) ? Tmax[row * 32 + lane] : -INFINITY;
    float gmax = tm;
    #pragma unroll
    for (int o = 1; o < 64; o <<= 1) gmax = fmaxf(gmax, __shfl_xor(gmax, o, 64));
    const float thr = gmax - 0.5f;

    if (lane == 0) cnt[w] = 0;
    __syncthreads();   // unconditional

    // phase 2: scan ONLY candidate tiles (512B each, float2/lane coalesced)
    for (int tile = 0; tile < 32; ++tile) {
        const float tmt = __shfl(tm, tile, 64);
        if (tmt >= thr) {
            const float2 v2 = *(const float2*)&L[row * 4096 + tile * 128 + lane * 2];
            if (v2.x >= thr) {
                int slot = atomicAdd(&cnt[w], 1);
                if (slot < 256) list[w][slot] = tile*128 + lane*2;
            }
            if (v2.y >= thr) {
                int slot = atomicAdd(&cnt[w], 1);
                if (slot < 256) list[w][slot] = tile*128 + lane*2 + 1;
            }
        }
    }
    __syncthreads();   // unconditional

    // phase 3: one candidate per lane, all dots in ONE exec pass
    int m = cnt[w]; if (m > 256) m = 256;
    float bv = -INFINITY;
    int   bi = 0x7fffffff;
    const float* qrow = Qf + row * 256;
    for (int base = 0; base < m; base += 64) {
        const int ci = base + lane;
        if (ci < m) {
            const int c = list[w][ci];
            float rv = dot256_f32(qrow, Kf + (size_t)c * 256) * 0.0625f;
            if (rv > bv || (rv == bv && c < bi)) { bv = rv; bi = c; }
        }
    }
    #pragma unroll
    for (int o = 1; o < 64; o <<= 1) {
        float ov = __shfl_xor(bv, o, 64);
        int   oi = __shfl_xor(bi, o, 64);
        if (ov > bv || (ov == bv && oi < bi)) { bv = ov; bi = oi; }
    }

    if (bi < 0) bi = 0;
    if (bi > 4095) bi = 4095;

    if (lane == 0) OutIdx[row] = (float)bi;

    float4 vv = ((const float4*)(Vf + (size_t)bi * 256))[lane];
    ((float4*)Zq)[row*64 + lane]  = vv;
    ((float4*)Zq2)[row*64 + lane] = vv;
}

extern "C" void kernel_launch(void* const* d_in, const int* in_sizes, int n_in,
                              void* d_out, int out_size, void* d_ws, size_t ws_size,
                              hipStream_t stream)
{
    (void)in_sizes; (void)n_in; (void)out_size;
    const float* hs = (const float*)d_in[0];
    const float* cb = (const float*)d_in[1];
    const float* wq = (const float*)d_in[2];
    const float* bq = (const float*)d_in[3];
    const float* wk = (const float*)d_in[4];
    const float* bk = (const float*)d_in[5];
    const float* wv = (const float*)d_in[6];
    const float* bv = (const float*)d_in[7];
    const float* gq = (const float*)d_in[8];
    const float* gk = (const float*)d_in[9];
    float* out = (float*)d_out;   // fp32: reference outputs are fp32/int32

    if (ws_size < 31457280u) return;  // need 30MB scratch

    // d_out layout (floats): logits @0 [32768*4096], idx @134217728 [32768],
    // z_q @134250496 [32768*256], z_q_2 @142639104 [32768*256].
    float* qf = out + 134250496ull;   // q lives in the z_q region until the FINAL refine store

    char* ws = (char*)d_ws;
    float* kf = (float*)ws;                                   //  4 MB: k raw -> k_norm (in place)
    float* vf = (float*)(ws + 4194304);                       //  4 MB: v
    __hip_bfloat16* qb = (__hip_bfloat16*)(ws + 8388608);     // 16 MB: q_norm bf16
    __hip_bfloat16* kb = (__hip_bfloat16*)(ws + 25165824);    //  2 MB: k_norm bf16
    float* tmax = (float*)(ws + 27262976);                    //  4 MB: per-tile row max

    gemm_fused<<<dim3(320, 2), 256, 0, stream>>>(hs, cb, wq, bq, wk, bk, wv, bv,
                                                 qf, kf, vf);
    rmsnorm_fused<<<9216, 256, 0, stream>>>(kf, qf, gk, gq, kb, qb);
    mfma_logits<<<8192, 256, 0, stream>>>(qb, kb, out, tmax);
    refine_argmax_fast<<<8192, 256, 0, stream>>>(out, tmax, qf, kf, vf,
        out + 134217728ull,   // idx
        out + 134250496ull,   // z_q   (aliases qf by design)
        out + 142639104ull);  // z_q_2
}

// Round 14
// 441.269 us; speedup vs baseline: 1.7945x; 1.0972x over previous
//
#include <hip/hip_runtime.h>
#include <hip/hip_bf16.h>

// AttentionForQuantizer: q/k/v proj + RMSNorm + logits(32768x4096) + argmax + gather.
// R14: R13 retry — __builtin_nontemporal_store requires a NATIVE clang vector type,
// not HIP's float4 struct; bit-cast through ext_vector_type f32x4 (same 16B layout,
// same dwordx4 nt store). Theory unchanged: the 512MB logits stream write-allocates
// in the 4MB/XCD L2 and evicts the Q/K working set; nt stores stop the pollution.
// Stored VALUES bit-identical to R12 (passed) — only cache policy changes.

#define NTOK 32768
#define NCODE 4096
#define DIM 256

typedef __bf16 bf16x8 __attribute__((ext_vector_type(8)));
typedef float f32x4 __attribute__((ext_vector_type(4)));

__device__ __forceinline__ void nt_store4(const float4& v, float* p) {
    f32x4 w; w[0] = v.x; w[1] = v.y; w[2] = v.z; w[3] = v.w;
    __builtin_nontemporal_store(w, (f32x4*)p);
}

// ---------------- fused fp32 GEMMs: k, v, q projections in one dispatch ----------------
// Body identical to R3..R12 gemm (same FMA order -> bit-identical results).
// Grid (320, 2): bx<32 -> k-proj, bx<64 -> v-proj, else q-proj (mb = (bx-64)*128).
__global__ __launch_bounds__(256, 2)
void gemm_fused(const float* __restrict__ hs, const float* __restrict__ cb,
                const float* __restrict__ wq, const float* __restrict__ bq,
                const float* __restrict__ wk, const float* __restrict__ bk,
                const float* __restrict__ wv, const float* __restrict__ bv,
                float* __restrict__ qf, float* __restrict__ kf, float* __restrict__ vf)
{
    __shared__ __align__(16) float Xs[32][132];  // [kk][m], padded
    __shared__ __align__(16) float Ws[32][132];  // [kk][n], padded
    const int t  = threadIdx.x;
    const int tm = t >> 4;         // 0..15
    const int tn = t & 15;         // 0..15

    const int bx = blockIdx.x;
    const float* X; const float* W; const float* bias; float* Y; int mb;
    if (bx < 32)      { X = cb; W = wk; bias = bk; Y = kf; mb = bx * 128; }
    else if (bx < 64) { X = cb; W = wv; bias = bv; Y = vf; mb = (bx - 32) * 128; }
    else              { X = hs; W = wq; bias = bq; Y = qf; mb = (bx - 64) * 128; }
    const int nb = blockIdx.y * 128;

    float acc[8][8];
    #pragma unroll
    for (int i = 0; i < 8; ++i)
        #pragma unroll
        for (int j = 0; j < 8; ++j) acc[i][j] = 0.f;

    const int sxm = t >> 1;          // X staging: row 0..127
    const int sxh = (t & 1) * 16;    // X staging: k-half base
    const int swk = t >> 3;          // W staging: kk 0..31
    const int swc = (t & 7) * 16;    // W staging: col base

    for (int kb = 0; kb < 256; kb += 32) {
        float4 xv[4], wv4[4];
        #pragma unroll
        for (int i = 0; i < 4; ++i) {
            xv[i]  = *(const float4*)&X[(size_t)(mb + sxm) * 256 + kb + sxh + 4 * i];
            wv4[i] = *(const float4*)&W[(size_t)(kb + swk) * 256 + nb + swc + 4 * i];
        }
        __syncthreads();  // previous iteration's LDS reads done before overwrite
        #pragma unroll
        for (int i = 0; i < 4; ++i) {
            Xs[sxh + 4*i + 0][sxm] = xv[i].x;
            Xs[sxh + 4*i + 1][sxm] = xv[i].y;
            Xs[sxh + 4*i + 2][sxm] = xv[i].z;
            Xs[sxh + 4*i + 3][sxm] = xv[i].w;
            *(float4*)&Ws[swk][swc + 4*i] = wv4[i];
        }
        __syncthreads();
        #pragma unroll 8
        for (int kk = 0; kk < 32; ++kk) {
            float4 a0 = *(const float4*)&Xs[kk][tm*8];
            float4 a1 = *(const float4*)&Xs[kk][tm*8 + 4];
            float4 b0 = *(const float4*)&Ws[kk][tn*8];
            float4 b1 = *(const float4*)&Ws[kk][tn*8 + 4];
            float av[8] = {a0.x,a0.y,a0.z,a0.w,a1.x,a1.y,a1.z,a1.w};
            float bw[8] = {b0.x,b0.y,b0.z,b0.w,b1.x,b1.y,b1.z,b1.w};
            #pragma unroll
            for (int i = 0; i < 8; ++i)
                #pragma unroll
                for (int j = 0; j < 8; ++j)
                    acc[i][j] = fmaf(av[i], bw[j], acc[i][j]);
        }
    }

    float4 bb0 = *(const float4*)&bias[nb + tn*8];
    float4 bb1 = *(const float4*)&bias[nb + tn*8 + 4];
    float bb[8] = {bb0.x,bb0.y,bb0.z,bb0.w,bb1.x,bb1.y,bb1.z,bb1.w};
    #pragma unroll
    for (int i = 0; i < 8; ++i) {
        const size_t row = (size_t)(mb + tm*8 + i);
        float4 o0 = {acc[i][0]+bb[0], acc[i][1]+bb[1], acc[i][2]+bb[2], acc[i][3]+bb[3]};
        float4 o1 = {acc[i][4]+bb[4], acc[i][5]+bb[5], acc[i][6]+bb[6], acc[i][7]+bb[7]};
        *(float4*)&Y[row*256 + nb + tn*8]     = o0;
        *(float4*)&Y[row*256 + nb + tn*8 + 4] = o1;
    }
}

// ---------------- fused RMSNorm: k rows + q rows in one dispatch ----------------
// Body identical to R3..R12 rmsnorm (same ops per row -> bit-identical).
__global__ __launch_bounds__(256)
void rmsnorm_fused(float* __restrict__ kf, float* __restrict__ qf,
                   const float* __restrict__ gk, const float* __restrict__ gq,
                   __hip_bfloat16* __restrict__ kb, __hip_bfloat16* __restrict__ qb)
{
    const int b = blockIdx.x;
    float* X; const float* g; __hip_bfloat16* Xb; size_t row;
    if (b < 1024) { X = kf; g = gk; Xb = kb; row = (size_t)b * 4 + (threadIdx.x >> 6); }
    else { X = qf; g = gq; Xb = qb; row = (size_t)(b - 1024) * 4 + (threadIdx.x >> 6); }

    const int lane = threadIdx.x & 63;
    float4 x = *(const float4*)&X[row*256 + lane*4];
    float ssq = fmaf(x.x, x.x, fmaf(x.y, x.y, fmaf(x.z, x.z, x.w * x.w)));
    #pragma unroll
    for (int o = 1; o < 64; o <<= 1) ssq += __shfl_xor(ssq, o, 64);
    const float r = 1.0f / sqrtf(ssq * (1.0f/256.0f) + 1e-5f);
    float4 gg = *(const float4*)&g[lane*4];
    float y0 = (x.x*r)*gg.x, y1 = (x.y*r)*gg.y, y2 = (x.z*r)*gg.z, y3 = (x.w*r)*gg.w;
    float4 y = {y0, y1, y2, y3};
    *(float4*)&X[row*256 + lane*4] = y;
    __hip_bfloat16 h0 = __float2bfloat16(y0), h1 = __float2bfloat16(y1);
    __hip_bfloat16 h2 = __float2bfloat16(y2), h3 = __float2bfloat16(y3);
    ushort4 p;
    p.x = *(unsigned short*)&h0; p.y = *(unsigned short*)&h1;
    p.z = *(unsigned short*)&h2; p.w = *(unsigned short*)&h3;
    ((ushort4*)Xb)[row*64 + lane] = p;
}

// ---------------- bf16 MFMA logits: Out[32768][4096] = fp32(clamp(Q @ K^T * 1/16)) ----
// R12 structure (m97 loop, both-sides LDS swizzle, LDS-bounce epilogue, Tmax, lb(256,4),
// XCD-chunked grid). Logits stores NONTEMPORAL — 512MB stream must not allocate in L2
// and evict the Q-band/K working set. Values bit-identical.
__device__ __forceinline__ void load_lds16(const void* g, void* l) {
    __builtin_amdgcn_global_load_lds((const __attribute__((address_space(1))) unsigned int*)g,
                                     (__attribute__((address_space(3))) unsigned int*)l, 16, 0, 0);
}

__global__ __launch_bounds__(256, 4)
void mfma_logits(const __hip_bfloat16* __restrict__ Qb, const __hip_bfloat16* __restrict__ Kb,
                 float* __restrict__ Out, float* __restrict__ Tmax)
{
    __shared__ __align__(16) char smem[33792];
    __hip_bfloat16* Asm = (__hip_bfloat16*)smem;            // [128 rows][64 k] bf16, 16KB
    __hip_bfloat16* Bsm = (__hip_bfloat16*)(smem + 16384);  // [128 rows][64 k] bf16, 16KB
    float*          Eps = (float*)smem;                     // [64 rows][128 cols] fp32, 32KB
    float*          Pmax = (float*)(smem + 32768);          // [128 rows][2 halves], 1KB

    const int t    = threadIdx.x;
    const int lane = t & 63;
    const int w    = t >> 6;
    const int wm = w >> 1, wn = w & 1;      // 2x2 wave grid of 64x64 quadrants

    const int bid = blockIdx.x;
    const int xcd = bid & 7;
    const int cid = bid >> 3;                // 0..1023
    const int mb  = (xcd * 32 + (cid & 31)) * 128;
    const int ctl = cid >> 5;                // col-tile 0..31
    const int nb  = ctl * 128;

    const int grow   = t >> 3;                       // + i*32 per issue
    const int gslot  = (t & 7) ^ ((t >> 3) & 7);
    const __hip_bfloat16* gA = Qb + (size_t)(mb + grow) * 256 + gslot * 8;
    const __hip_bfloat16* gB = Kb + (size_t)(nb + grow) * 256 + gslot * 8;
    __hip_bfloat16* lA = &Asm[w * 512];              // + i*2048 per issue (bf16 elems)
    __hip_bfloat16* lB = &Bsm[w * 512];

    const int fr = lane & 15;
    const int kq = lane >> 4;
    const int rswz = lane & 7;                       // row&7 for all our fragment rows
    const int ra0 = (wm * 64 + fr) * 64;             // A base elem offset (row*64)
    const int rb0 = (wn * 64 + fr) * 64;

    f32x4 acc[4][4];
    #pragma unroll
    for (int mi = 0; mi < 4; ++mi)
        #pragma unroll
        for (int ni = 0; ni < 4; ++ni) {
            acc[mi][ni][0] = 0.f; acc[mi][ni][1] = 0.f;
            acc[mi][ni][2] = 0.f; acc[mi][ni][3] = 0.f;
        }

    for (int ks = 0; ks < 4; ++ks) {
        const int k0 = ks * 64;
        #pragma unroll
        for (int i = 0; i < 4; ++i) {
            load_lds16(gA + (size_t)i * 32 * 256 + k0, lA + i * 2048);
            load_lds16(gB + (size_t)i * 32 * 256 + k0, lB + i * 2048);
        }
        __syncthreads();   // compiler drains vmcnt(0) before s_barrier [m97 evidence]

        #pragma unroll
        for (int kh = 0; kh < 2; ++kh) {            // ascending k == R4..R12 order
            bf16x8 af[4], bg[4];
            #pragma unroll
            for (int mi = 0; mi < 4; ++mi)
                af[mi] = *(const bf16x8*)&Asm[ra0 + mi*16*64 + (((kh<<2) + kq) ^ rswz) * 8];
            #pragma unroll
            for (int ni = 0; ni < 4; ++ni)
                bg[ni] = *(const bf16x8*)&Bsm[rb0 + ni*16*64 + (((kh<<2) + kq) ^ rswz) * 8];
            #pragma unroll
            for (int mi = 0; mi < 4; ++mi)
                #pragma unroll
                for (int ni = 0; ni < 4; ++ni)
                    acc[mi][ni] = __builtin_amdgcn_mfma_f32_16x16x32_bf16(
                        af[mi], bg[ni], acc[mi][ni], 0, 0, 0);
        }
        __syncthreads();   // LDS reads done before next K-step overwrites / epilogue
    }

    // ---- per-row partial maxima from acc regs (row = wm*64+mi*16+(lane>>4)*4+j) ----
    #pragma unroll
    for (int mi = 0; mi < 4; ++mi)
        #pragma unroll
        for (int j = 0; j < 4; ++j) {
            float mx = fmaxf(fmaxf(acc[mi][0][j], acc[mi][1][j]),
                             fmaxf(acc[mi][2][j], acc[mi][3][j]));
            #pragma unroll
            for (int o = 1; o < 16; o <<= 1) mx = fmaxf(mx, __shfl_xor(mx, o, 64));
            if ((lane & 15) == 0)
                Pmax[(wm*64 + mi*16 + (lane>>4)*4 + j)*2 + wn] = mx;
        }

    // ---- epilogue: LDS bounce -> coalesced full-row dwordx4 NONTEMPORAL stores ----
    const int cr = (lane >> 4) * 4;
    const int cc = lane & 15;
    #pragma unroll
    for (int c = 0; c < 2; ++c) {                    // chunk: rows [c*64, c*64+64)
        if (wm == c) {
            #pragma unroll
            for (int mi = 0; mi < 4; ++mi)
                #pragma unroll
                for (int ni = 0; ni < 4; ++ni) {
                    const int lrow = mi*16 + cr;                  // 0..63 within chunk
                    const int lcol = wn*64 + ni*16 + cc;          // 0..127
                    #pragma unroll
                    for (int j = 0; j < 4; ++j) {
                        float v = acc[mi][ni][j] * 0.0625f;
                        v = fminf(fmaxf(v, -16.0f), 16.0f);
                        Eps[(lrow + j) * 128 + lcol] = v;
                    }
                }
        }
        __syncthreads();   // bounce tile (and, first pass, Pmax) complete
        #pragma unroll
        for (int it = 0; it < 8; ++it) {
            const int p   = it * 1024 + t * 4;       // linear word index in [64][128]
            const int row = p >> 7;
            const int col = p & 127;
            float4 v = *(const float4*)&Eps[p];
            nt_store4(v, &Out[(size_t)(mb + c*64 + row) * 4096 + nb + col]);
        }
        __syncthreads();   // chunk read done before next chunk overwrites
    }

    // ---- Tmax: max is monotone under clamp(0.0625*x) -> equals max of stored values.
    // Tmax is re-read by refine -> stays cached (no nt).
    if (t < 128) {
        float raw = fmaxf(Pmax[t*2], Pmax[t*2 + 1]);
        float v = raw * 0.0625f;
        v = fminf(fmaxf(v, -16.0f), 16.0f);
        Tmax[(size_t)(mb + t) * 32 + ctl] = v;
    }
}

// ---------------- FROZEN canonical fp32 dot (argmax determinism anchor) ----------------
// DO NOT change the summation structure in future rounds. R3..R12 PASSED with this
// exact sequence (0 argmax flips vs numpy on the fixed dataset) — keep bit-identical.
__device__ __forceinline__ float dot256_f32(const float* __restrict__ a, const float* __restrict__ b)
{
    float s0 = 0.f, s1 = 0.f, s2 = 0.f, s3 = 0.f;
    #pragma unroll 8
    for (int j = 0; j < 64; ++j) {
        float4 x = ((const float4*)a)[j];
        float4 y = ((const float4*)b)[j];
        s0 = fmaf(x.x, y.x, s0);
        s1 = fmaf(x.y, y.y, s1);
        s2 = fmaf(x.z, y.z, s2);
        s3 = fmaf(x.w, y.w, s3);
    }
    return (s0 + s1) + (s2 + s3);
}

// ---------------- refine (fast): Tmax-pruned candidate scan + frozen dots ----------------
// Logic identical to R8..R12 (passed); z_q/z_q_2/idx stores NONTEMPORAL (outputs,
// never re-read; Qf alias reads complete before the store via the bi data dependence).
__global__ __launch_bounds__(256)
void refine_argmax_fast(const float* __restrict__ L, const float* __restrict__ Tmax,
                        const float* __restrict__ Qf, const float* __restrict__ Kf,
                        const float* __restrict__ Vf, float* __restrict__ OutIdx,
                        float* __restrict__ Zq, float* __restrict__ Zq2)
{
    __shared__ int cnt[4];
    __shared__ int list[4][256];
    const int lane = threadIdx.x & 63;
    const int w    = threadIdx.x >> 6;
    const size_t row = (size_t)blockIdx.x * 4 + w;

    // phase 1: row max from 32 tile maxima
    float tm = (lane < 32) ? Tmax[row * 32 + lane] : -INFINITY;
    float gmax = tm;
    #pragma unroll
    for (int o = 1; o < 64; o <<= 1) gmax = fmaxf(gmax, __shfl_xor(gmax, o, 64));
    const float thr = gmax - 0.5f;

    if (lane == 0) cnt[w] = 0;
    __syncthreads();   // unconditional

    // phase 2: scan ONLY candidate tiles (512B each, float2/lane coalesced)
    for (int tile = 0; tile < 32; ++tile) {
        const float tmt = __shfl(tm, tile, 64);
        if (tmt >= thr) {
            const float2 v2 = *(const float2*)&L[row * 4096 + tile * 128 + lane * 2];
            if (v2.x >= thr) {
                int slot = atomicAdd(&cnt[w], 1);
                if (slot < 256) list[w][slot] = tile*128 + lane*2;
            }
            if (v2.y >= thr) {
                int slot = atomicAdd(&cnt[w], 1);
                if (slot < 256) list[w][slot] = tile*128 + lane*2 + 1;
            }
        }
    }
    __syncthreads();   // unconditional

    // phase 3: one candidate per lane, all dots in ONE exec pass
    int m = cnt[w]; if (m > 256) m = 256;
    float bv = -INFINITY;
    int   bi = 0x7fffffff;
    const float* qrow = Qf + row * 256;
    for (int base = 0; base < m; base += 64) {
        const int ci = base + lane;
        if (ci < m) {
            const int c = list[w][ci];
            float rv = dot256_f32(qrow, Kf + (size_t)c * 256) * 0.0625f;
            if (rv > bv || (rv == bv && c < bi)) { bv = rv; bi = c; }
        }
    }
    #pragma unroll
    for (int o = 1; o < 64; o <<= 1) {
        float ov = __shfl_xor(bv, o, 64);
        int   oi = __shfl_xor(bi, o, 64);
        if (ov > bv || (ov == bv && oi < bi)) { bv = ov; bi = oi; }
    }

    if (bi < 0) bi = 0;
    if (bi > 4095) bi = 4095;

    if (lane == 0) __builtin_nontemporal_store((float)bi, &OutIdx[row]);

    float4 vv = ((const float4*)(Vf + (size_t)bi * 256))[lane];
    nt_store4(vv, (float*)&((float4*)Zq)[row*64 + lane]);
    nt_store4(vv, (float*)&((float4*)Zq2)[row*64 + lane]);
}

extern "C" void kernel_launch(void* const* d_in, const int* in_sizes, int n_in,
                              void* d_out, int out_size, void* d_ws, size_t ws_size,
                              hipStream_t stream)
{
    (void)in_sizes; (void)n_in; (void)out_size;
    const float* hs = (const float*)d_in[0];
    const float* cb = (const float*)d_in[1];
    const float* wq = (const float*)d_in[2];
    const float* bq = (const float*)d_in[3];
    const float* wk = (const float*)d_in[4];
    const float* bk = (const float*)d_in[5];
    const float* wv = (const float*)d_in[6];
    const float* bv = (const float*)d_in[7];
    const float* gq = (const float*)d_in[8];
    const float* gk = (const float*)d_in[9];
    float* out = (float*)d_out;   // fp32: reference outputs are fp32/int32

    if (ws_size < 31457280u) return;  // need 30MB scratch

    // d_out layout (floats): logits @0 [32768*4096], idx @134217728 [32768],
    // z_q @134250496 [32768*256], z_q_2 @142639104 [32768*256].
    float* qf = out + 134250496ull;   // q lives in the z_q region until the FINAL refine store

    char* ws = (char*)d_ws;
    float* kf = (float*)ws;                                   //  4 MB: k raw -> k_norm (in place)
    float* vf = (float*)(ws + 4194304);                       //  4 MB: v
    __hip_bfloat16* qb = (__hip_bfloat16*)(ws + 8388608);     // 16 MB: q_norm bf16
    __hip_bfloat16* kb = (__hip_bfloat16*)(ws + 25165824);    //  2 MB: k_norm bf16
    float* tmax = (float*)(ws + 27262976);                    //  4 MB: per-tile row max

    gemm_fused<<<dim3(320, 2), 256, 0, stream>>>(hs, cb, wq, bq, wk, bk, wv, bv,
                                                 qf, kf, vf);
    rmsnorm_fused<<<9216, 256, 0, stream>>>(kf, qf, gk, gq, kb, qb);
    mfma_logits<<<8192, 256, 0, stream>>>(qb, kb, out, tmax);
    refine_argmax_fast<<<8192, 256, 0, stream>>>(out, tmax, qf, kf, vf,
        out + 134217728ull,   // idx
        out + 134250496ull,   // z_q   (aliases qf by design)
        out + 142639104ull);  // z_q_2
}